// Round 4
// baseline (625.694 us; speedup 1.0000x reference)
//
#include <hip/hip_runtime.h>

typedef unsigned short u16;
typedef unsigned int   u32;

#define JF 247   // folded inner dim: 64(k0 x) + 64(k1 x) + 64(k2 x) + 55(time, k-summed)

// ---- workspace layout (float offsets); total ~7.16 MB ----
#define OFF_SUP    0         // 200x200 row-major
#define OFF_SUPT   40000     // supT[m][n]
#define OFF_SUP2T  80000     // sup2T[m][n]
#define OFF_BIAS   120000    // 200x128
#define OFF_RCPHE  145600
#define OFF_RCPN   145664
#define OFF_RCPHN  145920
#define OFF_RCPE   145984
#define OFF_A1     146112    // 39x200 counts
#define OFF_A1E    153984    // 23x100 counts
#define OFF_ANODET 156352    // ANODET[m][n] = A_node[n][m]
#define OFF_AEDGET 196352    // AEDGET[j][m] = A_edge[m][j]
#define OFF_WNODE  206352    // 64x32 = [Wns | Wna] fp32
#define OFF_WEDGE  208400    // 16x16 = [Wes | Wea] fp32
#define OFF_WHOC   208656    // 16x16 fp32
#define OFF_BHOC   208912    // 16 fp32
#define OFF_WF16   209024    // u16 wFold [200][247][64]

__device__ __forceinline__ float us2f(u16 u){
  union { float f; u32 i; } v; v.i = ((u32)u) << 16; return v.f;
}
__device__ __forceinline__ u16 f2us(float f){
  u32 u = __float_as_uint(f);
  u += 0x7FFF + ((u >> 16) & 1);           // RNE
  return (u16)(u >> 16);
}

// ---------------- precompute 1: sup row-softmax, wFold(bf16), bias, count matrices ----------------
__global__ __launch_bounds__(256) void k_pre1(
    const float* __restrict__ E, const float* __restrict__ Wp, const float* __restrict__ biasP,
    const float* __restrict__ Wns, const float* __restrict__ Wna,
    const float* __restrict__ Wes, const float* __restrict__ Wea,
    const float* __restrict__ Whoc, const float* __restrict__ bhoc,
    const int* __restrict__ hed, const int* __restrict__ hnd,
    float* __restrict__ ws)
{
  const int n = blockIdx.x, t = threadIdx.x;
  __shared__ float Ef[2000];
  __shared__ float arow[200];
  __shared__ float red[256];
  __shared__ int A1i[7800];
  __shared__ int A1ei[2300];
  for (int i=t;i<2000;i+=256) Ef[i] = E[i];
  __syncthreads();
  const float* En = &Ef[n*10];
  for (int m=t;m<200;m+=256){
    float s=0.f;
    #pragma unroll
    for (int d=0;d<10;d++) s += En[d]*Ef[m*10+d];
    arow[m] = fmaxf(s,0.f);
  }
  __syncthreads();
  float mv = -1e30f;
  for (int m=t;m<200;m+=256) mv = fmaxf(mv, arow[m]);
  red[t]=mv; __syncthreads();
  for (int s=128;s>0;s>>=1){ if(t<s) red[t]=fmaxf(red[t],red[t+s]); __syncthreads(); }
  mv = red[0]; __syncthreads();
  float sv=0.f;
  for (int m=t;m<200;m+=256) sv += __expf(arow[m]-mv);
  red[t]=sv; __syncthreads();
  for (int s=128;s>0;s>>=1){ if(t<s) red[t]+=red[t+s]; __syncthreads(); }
  const float inv = 1.f/red[0];
  for (int m=t;m<200;m+=256){
    float e = __expf(arow[m]-mv)*inv;
    ws[OFF_SUP  + n*200+m] = e;
    ws[OFF_SUPT + m*200+n] = e;
  }
  // wFold[n][j][o] bf16: j<192 -> (k=j>>6, i=j&63); j>=192 -> time col i=64+(j-192), summed over k
  u16* wF16 = (u16*)(ws + OFF_WF16) + (size_t)n*(JF*64);
  for (int idx=t; idx<JF*64; idx+=256){
    int j = idx>>6, o = idx&63;
    float acc=0.f;
    if (j<192){
      int k=j>>6, i=j&63;
      #pragma unroll
      for (int d=0;d<10;d++) acc += En[d]*Wp[((size_t)(d*3+k)*119+i)*64+o];
    } else {
      int i = 64 + (j-192);
      #pragma unroll
      for (int k=0;k<3;k++)
        for (int d=0;d<10;d++) acc += En[d]*Wp[((size_t)(d*3+k)*119+i)*64+o];
    }
    wF16[idx]=f2us(acc);
  }
  for (int o=t;o<128;o+=256){
    float acc=0.f;
    #pragma unroll
    for (int d=0;d<10;d++) acc += En[d]*biasP[d*128+o];
    ws[OFF_BIAS + n*128+o]=acc;
  }
  if (n==0){
    for (int i=t;i<7800;i+=256) A1i[i]=0;
    for (int i=t;i<2300;i+=256) A1ei[i]=0;
    __syncthreads();
    for (int e=t;e<800;e+=256) atomicAdd(&A1i[hed[800+e]*200 + hed[e]], 1);
    for (int e=t;e<400;e+=256) atomicAdd(&A1ei[hnd[400+e]*100 + hnd[e]], 1);
    __syncthreads();
    for (int i=t;i<7800;i+=256) ws[OFF_A1+i]=(float)A1i[i];
    for (int i=t;i<2300;i+=256) ws[OFF_A1E+i]=(float)A1ei[i];
    for (int h=t;h<39;h+=256){ int s=0; for(int m=0;m<200;m++) s+=A1i[h*200+m]; ws[OFF_RCPHE+h]=1.f/fmaxf((float)s,1.f); }
    for (int m=t;m<200;m+=256){ int s=0; for(int h=0;h<39;h++) s+=A1i[h*200+m]; ws[OFF_RCPN+m]=1.f/fmaxf((float)s,1.f); }
    for (int h=t;h<23;h+=256){ int s=0; for(int m=0;m<100;m++) s+=A1ei[h*100+m]; ws[OFF_RCPHN+h]=1.f/fmaxf((float)s,1.f); }
    for (int m=t;m<100;m+=256){ int s=0; for(int h=0;h<23;h++) s+=A1ei[h*100+m]; ws[OFF_RCPE+m]=1.f/fmaxf((float)s,1.f); }
  }
  if (n==1){
    for (int idx=t;idx<2048;idx+=256){ int j=idx>>5,c=idx&31;
      ws[OFF_WNODE+idx]= (c<16? Wns[j*16+c] : Wna[j*16+(c-16)]); }
    { int j=t>>4, c=t&15;
      ws[OFF_WEDGE+t]= (c<8? Wes[j*8+c] : Wea[j*8+(c-8)]);
      ws[OFF_WHOC+t]= Whoc[t]; }
    if (t<16) ws[OFF_BHOC+t]= bhoc[t];
  }
}

// ---------------- precompute 2: sup^2, A_node, A_edge (all transposed) ----------------
__global__ __launch_bounds__(256) void k_pre2(float* __restrict__ ws)
{
  const int blk = blockIdx.x, t = threadIdx.x;
  __shared__ float rowp[200];
  __shared__ float colw[64];
  if (blk < 200){
    const int n = blk;
    for (int m=t;m<200;m+=256) rowp[m]=ws[OFF_SUP+n*200+m];
    for (int h=t;h<39;h+=256) colw[h]=ws[OFF_A1+h*200+n]*ws[OFF_RCPHE+h];
    __syncthreads();
    for (int j=t;j<200;j+=256){
      float acc=0.f;
      for (int m=0;m<200;m++) acc += rowp[m]*ws[OFF_SUP+m*200+j];
      ws[OFF_SUP2T + j*200 + n] = acc;     // sup2T[j][n] = sup2[n][j]
    }
    const float rn = ws[OFF_RCPN+n];
    for (int m=t;m<200;m+=256){
      float acc=0.f;
      for (int h=0;h<39;h++) acc += colw[h]*ws[OFF_A1+h*200+m];
      ws[OFF_ANODET + m*200 + n] = acc*rn; // A_node[n][m]
    }
  } else {
    const int n = blk-200;
    for (int h=t;h<23;h+=256) colw[h]=ws[OFF_A1E+h*100+n]*ws[OFF_RCPHN+h];
    __syncthreads();
    const float rn = ws[OFF_RCPE+n];
    for (int m=t;m<100;m+=256){
      float acc=0.f;
      for (int h=0;h<23;h++) acc += colw[h]*ws[OFF_A1E+h*100+m];
      ws[OFF_AEDGET + m*100 + n] = acc*rn; // A_edge[n][m] stored at [m][n]
    }
  }
}

// ---------------- stage A: xg_k[b,n,c] = sum_m sup_k[n,m] * x[b,m,c]  ->  d_out scratch (fp32) ----------------
// xg1 -> out[b][n][0:64), xg2 -> out[b][n][64:128)  (overwritten later by stageB / chain)
__global__ __launch_bounds__(256) void k_stageA(
    const float* __restrict__ x, const float* __restrict__ ws,
    float* __restrict__ outp)
{
  const int b = blockIdx.x, t = threadIdx.x;
  const int c = t&63;
  const int wv = __builtin_amdgcn_readfirstlane(t>>6);
  __shared__ float xs[12800];              // x[b] as [m][c] fp32
  const float4* xp = (const float4*)(x + (size_t)b*12800);
  for (int i=t;i<3200;i+=256){
    float4 p = xp[i];
    xs[4*i]=p.x; xs[4*i+1]=p.y; xs[4*i+2]=p.z; xs[4*i+3]=p.w;
  }
  __syncthreads();
  #pragma unroll
  for (int kk=0;kk<2;kk++){
    const float* ST = ws + (kk? OFF_SUP2T : OFF_SUPT);   // [m][n]
    const int ch = kk? 64 : 0;
    for (int g=wv; g<13; g+=4){
      const int n0 = g*16;
      float acc[16];
      #pragma unroll
      for (int r=0;r<16;r++) acc[r]=0.f;
      for (int m=0;m<200;m++){
        float xv = xs[m*64+c];
        const float* sr = ST + m*200 + n0;  // wave-uniform address -> scalar loads
        #pragma unroll
        for (int r=0;r<16;r++) acc[r] += sr[r]*xv;   // overread at n0=192 stays in
      }                                               // initialized ws; results discarded
      const int nr = (n0+16<=200)?16:(200-n0);
      for (int r=0;r<nr;r++)
        outp[((size_t)b*200 + n0 + r)*128 + ch + c] = acc[r];
    }
  }
}

// ---------------- stage B: out[:,:,0:64] = v(247) . wFold[n] + bias ----------------
__global__ __launch_bounds__(256) void k_stageB(
    const float* __restrict__ x, const float* __restrict__ xtime,
    const float* __restrict__ ws, float* __restrict__ outp)
{
  const int bt = blockIdx.x, n = blockIdx.y, t = threadIdx.x;
  const int b0 = bt*64, lane = t&63;
  const int wv = __builtin_amdgcn_readfirstlane(t>>6);
  __shared__ u16 vT[JF*65];                // [j][b-lane], bf16 staging
  for (int idx=t; idx<4096; idx+=256){
    int l=idx>>6, j=idx&63;
    vT[j*65+l] = f2us(x[((size_t)(b0+l)*200 + n)*64 + j]);
  }
  for (int idx=t; idx<4096; idx+=256){     // xg1 from out scratch ch[0:64)
    int l=idx>>6, j=idx&63;
    vT[(64+j)*65+l] = f2us(outp[((size_t)(b0+l)*200 + n)*128 + j]);
  }
  for (int idx=t; idx<4096; idx+=256){     // xg2 from out scratch ch[64:128)
    int l=idx>>6, j=idx&63;
    vT[(128+j)*65+l] = f2us(outp[((size_t)(b0+l)*200 + n)*128 + 64 + j]);
  }
  for (int idx=t; idx<64*55; idx+=256){
    int l=idx/55, j=idx-l*55;
    vT[(192+j)*65+l] = f2us(xtime[(size_t)(b0+l)*55 + j]);
  }
  __syncthreads();
  const int o0 = wv*16;
  float acc[16];
  #pragma unroll
  for (int q=0;q<16;q++) acc[q]=0.f;
  const u32* wp = (const u32*)(ws + OFF_WF16) + (size_t)n*(JF*32) + (o0>>1);
  for (int j=0;j<JF;j++){
    float vv = us2f(vT[j*65 + lane]);
    const u32* wr = wp + j*32;             // wave-uniform -> scalar dword loads
    #pragma unroll
    for (int q=0;q<8;q++){
      u32 p = wr[q];
      acc[2*q]   += vv * __uint_as_float(p<<16);
      acc[2*q+1] += vv * __uint_as_float(p & 0xFFFF0000u);
    }
  }
  const float* bs = ws + OFF_BIAS + n*128 + o0;
  float* op = outp + ((size_t)(b0+lane)*200 + n)*128 + o0;   // block-private overwrite of xg1
  #pragma unroll
  for (int q=0;q<16;q++) op[q] = acc[q] + bs[q];
}

// ---------------- per-batch chain: out[:,:,64:128] ----------------
__global__ __launch_bounds__(256) void k_chain(
    const float* __restrict__ x, const float* __restrict__ xe,
    const float* __restrict__ hodge, const float* __restrict__ inc,
    const float* __restrict__ ws, float* __restrict__ outp)
{
  const int b = blockIdx.x, t = threadIdx.x;
  const int lane = t&63;
  const int wv = __builtin_amdgcn_readfirstlane(t>>6);
  __shared__ __align__(16) float pool[13652];  // 54.6 KB multi-phase pool
  __shared__ __align__(16) float xea[800];
  __shared__ u16 xeT[16*101];
  u16*   xbTu   = (u16*)pool;      // ph1: [j<64][nn<200] stride 201, bf16 (6432 fl)
  float* xa     = pool + 6432;     // ph1: 200x16 -> [6432,9632)
  u16*   hodgeTu= (u16*)pool;      // ph2: [j][m] stride 101, bf16 (5050 fl)
  float* hl     = pool + 6432;     // ph2: 100x17 -> [6432,8132)
  float* xeh    = pool + 8132;     // ph2: 100x16 -> [8132,9732)
  float* hh     = pool + 10052;    // ph2/3: 100x36 -> [10052,13652)
  u16*   incTu  = (u16*)pool;      // ph3: [m][nn] stride 201 (10050 fl)

  // --- stage x[b] transposed (bf16) ---
  {
    const float* xf = x + (size_t)b*12800;
    for (int idx=t; idx<12800; idx+=256){
      int nn=idx>>6, j=idx&63;
      xbTu[j*201+nn] = f2us(xf[idx]);
    }
  }
  __syncthreads();
  // --- xself -> out[64:80); xa = x @ Wna ---
  if (t < 200){
    const int nn = t;
    float as[16], aa[16];
    #pragma unroll
    for (int c=0;c<16;c++){ as[c]=0.f; aa[c]=0.f; }
    for (int j=0;j<64;j++){
      float xv = us2f(xbTu[j*201+nn]);
      const float* Wn = ws + OFF_WNODE + j*32;   // uniform -> scalar loads
      #pragma unroll
      for (int c=0;c<16;c++){ as[c] += xv*Wn[c]; aa[c] += xv*Wn[16+c]; }
    }
    const float* bs = ws + OFF_BIAS + nn*128 + 64;
    float* op = outp + ((size_t)b*200 + nn)*128 + 64;
    #pragma unroll
    for (int c=0;c<16;c++){ op[c] = as[c] + bs[c]; xa[nn*16+c] = aa[c]; }
  }
  __syncthreads();
  // --- hn = A_node @ xa -> out[80:96) ---
  if (lane < 50){
    const int nn = wv*50 + lane;
    float acc[16];
    #pragma unroll
    for (int c=0;c<16;c++) acc[c]=0.f;
    for (int m=0;m<200;m++){
      float av = ws[OFF_ANODET + m*200 + nn];
      #pragma unroll
      for (int q=0;q<4;q++){
        const float4 h = *(const float4*)&xa[m*16 + q*4];
        acc[q*4+0]+=av*h.x; acc[q*4+1]+=av*h.y; acc[q*4+2]+=av*h.z; acc[q*4+3]+=av*h.w;
      }
    }
    const float* bs = ws + OFF_BIAS + nn*128 + 80;
    float* op = outp + ((size_t)b*200 + nn)*128 + 80;
    #pragma unroll
    for (int c=0;c<16;c++) op[c] = acc[c] + bs[c];
  }
  __syncthreads();
  // --- stage x_e transposed + hodge transposed (xbT/xa dead) ---
  {
    const float* xef = xe + (size_t)b*1600;
    for (int idx=t; idx<1600; idx+=256){
      int m=idx>>4, j=idx&15;
      xeT[j*101+m] = f2us(xef[idx]);
    }
    for (int idx=t; idx<10000; idx+=256){
      int m=idx/100, j=idx-m*100;
      hodgeTu[j*101+m] = f2us(hodge[idx]);
    }
  }
  __syncthreads();
  // --- xes -> xeh[:,0:8); xea = x_e @ Wea ---
  if (t < 100){
    const int m = t;
    float as[8], aa[8];
    #pragma unroll
    for (int c=0;c<8;c++){ as[c]=0.f; aa[c]=0.f; }
    for (int j=0;j<16;j++){
      float xv = us2f(xeT[j*101+m]);
      const float* We = ws + OFF_WEDGE + j*16;
      #pragma unroll
      for (int c=0;c<8;c++){ as[c]+=xv*We[c]; aa[c]+=xv*We[8+c]; }
    }
    #pragma unroll
    for (int c=0;c<8;c++){ xeh[m*16+c]=as[c]; xea[m*8+c]=aa[c]; }
  }
  __syncthreads();
  // --- hne = A_edge @ xea -> xeh[:,8:16) ---
  if (t < 100){
    const int m = t;
    float acc[8];
    #pragma unroll
    for (int c=0;c<8;c++) acc[c]=0.f;
    for (int j=0;j<100;j++){
      float av = ws[OFF_AEDGET + j*100 + m];
      const float4 h0 = *(const float4*)&xea[j*8];
      const float4 h1 = *(const float4*)&xea[j*8+4];
      acc[0]+=av*h0.x; acc[1]+=av*h0.y; acc[2]+=av*h0.z; acc[3]+=av*h0.w;
      acc[4]+=av*h1.x; acc[5]+=av*h1.y; acc[6]+=av*h1.z; acc[7]+=av*h1.w;
    }
    #pragma unroll
    for (int c=0;c<8;c++) xeh[m*16+8+c]=acc[c];
  }
  __syncthreads();
  // --- hl = hodge @ xeh ---
  if (t < 200){
    const int m  = (t<100)? t : t-100;
    const int ch = (t<100)? 0 : 8;
    float acc[8];
    #pragma unroll
    for (int c=0;c<8;c++) acc[c]=0.f;
    for (int j=0;j<100;j++){
      float hv = us2f(hodgeTu[j*101+m]);
      const float4 h0 = *(const float4*)&xeh[j*16+ch];
      const float4 h1 = *(const float4*)&xeh[j*16+ch+4];
      acc[0]+=hv*h0.x; acc[1]+=hv*h0.y; acc[2]+=hv*h0.z; acc[3]+=hv*h0.w;
      acc[4]+=hv*h1.x; acc[5]+=hv*h1.y; acc[6]+=hv*h1.z; acc[7]+=hv*h1.w;
    }
    #pragma unroll
    for (int c=0;c<8;c++) hl[m*17+ch+c]=acc[c];
  }
  __syncthreads();
  // --- hconv = hl @ Whoc + bhoc -> hh[:,16:32) ---
  if (t < 100){
    const int m = t;
    float acc[16];
    #pragma unroll
    for (int c=0;c<16;c++) acc[c]=0.f;
    for (int j=0;j<16;j++){
      float hv = hl[m*17+j];
      const float* Wh = ws + OFF_WHOC + j*16;
      #pragma unroll
      for (int c=0;c<16;c++) acc[c]+=hv*Wh[c];
    }
    const float* bh = ws + OFF_BHOC;
    #pragma unroll
    for (int c=0;c<16;c++) hh[m*36+16+c] = acc[c]+bh[c];
  }
  __syncthreads();
  // --- hh[:,0:16) = xeh ---
  for (int idx=t; idx<1600; idx+=256){
    int m=idx>>4, c=idx&15;
    hh[m*36+c] = xeh[m*16+c];
  }
  __syncthreads();
  // --- stage incT (hodgeT/hl/xeh dead) ---
  for (int idx=t; idx<20000; idx+=256){
    int n2=idx/100, m=idx-n2*100;
    incTu[m*201+n2] = f2us(inc[idx]);
  }
  __syncthreads();
  // --- out[96:128) = inc @ hh + bias ---
  if (lane < 50){
    const int nn = wv*50 + lane;
    float acc[32];
    #pragma unroll
    for (int c=0;c<32;c++) acc[c]=0.f;
    for (int m=0;m<100;m++){
      float iv = us2f(incTu[m*201+nn]);
      #pragma unroll
      for (int q=0;q<8;q++){
        const float4 h = *(const float4*)&hh[m*36 + q*4];
        acc[q*4+0]+=iv*h.x; acc[q*4+1]+=iv*h.y; acc[q*4+2]+=iv*h.z; acc[q*4+3]+=iv*h.w;
      }
    }
    const float* bs = ws + OFF_BIAS + nn*128 + 96;
    float* op = outp + ((size_t)b*200 + nn)*128 + 96;
    #pragma unroll
    for (int c=0;c<32;c++) op[c] = acc[c]+bs[c];
  }
}

extern "C" void kernel_launch(void* const* d_in, const int* in_sizes, int n_in,
                              void* d_out, int out_size, void* d_ws, size_t ws_size,
                              hipStream_t stream)
{
  (void)in_sizes; (void)n_in; (void)out_size; (void)ws_size;
  const float* x     = (const float*)d_in[0];
  const float* xe    = (const float*)d_in[1];
  const float* xtime = (const float*)d_in[2];
  // d_in[3] = x_window : unused by the reference
  const float* E     = (const float*)d_in[4];
  const float* hodge = (const float*)d_in[5];
  const float* inc   = (const float*)d_in[6];
  const int* hed     = (const int*)d_in[7];
  const int* hnd     = (const int*)d_in[8];
  const float* Wp    = (const float*)d_in[9];
  const float* biasP = (const float*)d_in[10];
  const float* Wns   = (const float*)d_in[11];
  const float* Wna   = (const float*)d_in[12];
  const float* Wes   = (const float*)d_in[13];
  const float* Wea   = (const float*)d_in[14];
  const float* Whoc  = (const float*)d_in[15];
  const float* bhoc  = (const float*)d_in[16];
  float* ws  = (float*)d_ws;
  float* outp = (float*)d_out;

  k_pre1<<<200, 256, 0, stream>>>(E, Wp, biasP, Wns, Wna, Wes, Wea, Whoc, bhoc, hed, hnd, ws);
  k_pre2<<<300, 256, 0, stream>>>(ws);
  k_stageA<<<512, 256, 0, stream>>>(x, ws, outp);
  k_stageB<<<dim3(8, 200), 256, 0, stream>>>(x, xtime, ws, outp);
  k_chain<<<512, 256, 0, stream>>>(x, xe, hodge, inc, ws, outp);
}

// Round 5
// 321.419 us; speedup vs baseline: 1.9467x; 1.9467x over previous
//
#include <hip/hip_runtime.h>

typedef unsigned short u16;
typedef unsigned int   u32;
typedef __attribute__((ext_vector_type(8))) short short8;
typedef __attribute__((ext_vector_type(4))) float f32x4;

// ---- workspace layout (float offsets); total 1,771,180 fl = 7,084,720 B ----
#define OFF_SUP       0        // 200x200 fp32 row-major sup1
#define OFF_SUP2T     40000    // SUP2T[m][n] = sup2[n][m] fp32
#define OFF_BIAS      80000    // 200x128 fp32
#define OFF_RCPHE     105600
#define OFF_RCPN      105664
#define OFF_RCPHN     105920
#define OFF_RCPE      105984
#define OFF_A1        106112   // 39x200
#define OFF_A1E       113912   // 23x100
#define OFF_WNODE     116212   // 64x32 fp32 [Wns|Wna]
#define OFF_WEDGE     118260   // 16x16 fp32 [Wes|Wea]
#define OFF_WHOC      118516   // 16x16 fp32
#define OFF_BHOC      118772   // 16 fp32
#define OFF_ANODET16  118788   // u16[40000]  A_node[n][m] stored [m*200+n], bf16
#define OFF_AEDGET16  138788   // u16[10000]  A_edge[m][j] stored [j*100+m], bf16
#define OFF_SUPB      143788   // u16[93184]  sup B-fragments [(kk*13+nt)*7+kt][lane][8]
#define OFF_WF16      190380   // u16[3161600] wFold [n][247 j][64 o] bf16 linear

__device__ __forceinline__ float us2f(u16 u){
  union { float f; u32 i; } v; v.i = ((u32)u) << 16; return v.f;
}
__device__ __forceinline__ u16 f2us(float f){
  u32 u = __float_as_uint(f);
  u += 0x7FFF + ((u >> 16) & 1);           // RNE
  return (u16)(u >> 16);
}

// ---------------- pre1: sup row-softmax, wFold(bf16 linear), bias, count matrices ----------------
__global__ __launch_bounds__(256) void k_pre1(
    const float* __restrict__ E, const float* __restrict__ Wp, const float* __restrict__ biasP,
    const float* __restrict__ Wns, const float* __restrict__ Wna,
    const float* __restrict__ Wes, const float* __restrict__ Wea,
    const float* __restrict__ Whoc, const float* __restrict__ bhoc,
    const int* __restrict__ hed, const int* __restrict__ hnd,
    float* __restrict__ ws)
{
  const int n = blockIdx.x, t = threadIdx.x;
  __shared__ float Ef[2000];
  __shared__ float arow[200];
  __shared__ float red[256];
  __shared__ int A1i[7800];
  __shared__ int A1ei[2300];
  for (int i=t;i<2000;i+=256) Ef[i] = E[i];
  __syncthreads();
  const float* En = &Ef[n*10];
  for (int m=t;m<200;m+=256){
    float s=0.f;
    #pragma unroll
    for (int d=0;d<10;d++) s += En[d]*Ef[m*10+d];
    arow[m] = fmaxf(s,0.f);
  }
  __syncthreads();
  float mv = -1e30f;
  for (int m=t;m<200;m+=256) mv = fmaxf(mv, arow[m]);
  red[t]=mv; __syncthreads();
  for (int s=128;s>0;s>>=1){ if(t<s) red[t]=fmaxf(red[t],red[t+s]); __syncthreads(); }
  mv = red[0]; __syncthreads();
  float sv=0.f;
  for (int m=t;m<200;m+=256) sv += __expf(arow[m]-mv);
  red[t]=sv; __syncthreads();
  for (int s=128;s>0;s>>=1){ if(t<s) red[t]+=red[t+s]; __syncthreads(); }
  const float inv = 1.f/red[0];
  for (int m=t;m<200;m+=256)
    ws[OFF_SUP + n*200+m] = __expf(arow[m]-mv)*inv;
  // wFold[n][j][o] bf16 linear: j<192 -> (k=j>>6, i=j&63); j>=192 -> time col, k-summed
  u16* wF16 = (u16*)(ws + OFF_WF16) + (size_t)n*(247*64);
  for (int idx=t; idx<247*64; idx+=256){
    int j = idx>>6, o = idx&63;
    float acc=0.f;
    if (j<192){
      int k=j>>6, i=j&63;
      #pragma unroll
      for (int d=0;d<10;d++) acc += En[d]*Wp[((size_t)(d*3+k)*119+i)*64+o];
    } else {
      int i = 64 + (j-192);
      #pragma unroll
      for (int k=0;k<3;k++)
        for (int d=0;d<10;d++) acc += En[d]*Wp[((size_t)(d*3+k)*119+i)*64+o];
    }
    wF16[idx]=f2us(acc);
  }
  for (int o=t;o<128;o+=256){
    float acc=0.f;
    #pragma unroll
    for (int d=0;d<10;d++) acc += En[d]*biasP[d*128+o];
    ws[OFF_BIAS + n*128+o]=acc;
  }
  if (n==0){
    for (int i=t;i<7800;i+=256) A1i[i]=0;
    for (int i=t;i<2300;i+=256) A1ei[i]=0;
    __syncthreads();
    for (int e=t;e<800;e+=256) atomicAdd(&A1i[hed[800+e]*200 + hed[e]], 1);
    for (int e=t;e<400;e+=256) atomicAdd(&A1ei[hnd[400+e]*100 + hnd[e]], 1);
    __syncthreads();
    for (int i=t;i<7800;i+=256) ws[OFF_A1+i]=(float)A1i[i];
    for (int i=t;i<2300;i+=256) ws[OFF_A1E+i]=(float)A1ei[i];
    for (int h=t;h<39;h+=256){ int s=0; for(int m=0;m<200;m++) s+=A1i[h*200+m]; ws[OFF_RCPHE+h]=1.f/fmaxf((float)s,1.f); }
    for (int m=t;m<200;m+=256){ int s=0; for(int h=0;h<39;h++) s+=A1i[h*200+m]; ws[OFF_RCPN+m]=1.f/fmaxf((float)s,1.f); }
    for (int h=t;h<23;h+=256){ int s=0; for(int m=0;m<100;m++) s+=A1ei[h*100+m]; ws[OFF_RCPHN+h]=1.f/fmaxf((float)s,1.f); }
    for (int m=t;m<100;m+=256){ int s=0; for(int h=0;h<23;h++) s+=A1ei[h*100+m]; ws[OFF_RCPE+m]=1.f/fmaxf((float)s,1.f); }
  }
  if (n==1){
    for (int idx=t;idx<2048;idx+=256){ int j=idx>>5,c=idx&31;
      ws[OFF_WNODE+idx]= (c<16? Wns[j*16+c] : Wna[j*16+(c-16)]); }
    { int j=t>>4, c=t&15;
      ws[OFF_WEDGE+t]= (c<8? Wes[j*8+c] : Wea[j*8+(c-8)]);
      ws[OFF_WHOC+t]= Whoc[t]; }
    if (t<16) ws[OFF_BHOC+t]= bhoc[t];
  }
}

// ---------------- pre2: sup^2 (transposed), A_node/A_edge (bf16, transposed) ----------------
__global__ __launch_bounds__(256) void k_pre2(float* __restrict__ ws)
{
  const int blk = blockIdx.x, t = threadIdx.x;
  __shared__ float rowp[200];
  __shared__ float colw[64];
  if (blk < 200){
    const int n = blk;
    for (int m=t;m<200;m+=256) rowp[m]=ws[OFF_SUP+n*200+m];
    for (int h=t;h<39;h+=256) colw[h]=ws[OFF_A1+h*200+n]*ws[OFF_RCPHE+h];
    __syncthreads();
    for (int j=t;j<200;j+=256){
      float acc=0.f;
      for (int m=0;m<200;m++) acc += rowp[m]*ws[OFF_SUP+m*200+j];
      ws[OFF_SUP2T + j*200 + n] = acc;     // sup2[n][j] at [j][n]
    }
    const float rn = ws[OFF_RCPN+n];
    u16* an16 = (u16*)(ws + OFF_ANODET16);
    for (int m=t;m<200;m+=256){
      float acc=0.f;
      for (int h=0;h<39;h++) acc += colw[h]*ws[OFF_A1+h*200+m];
      an16[m*200 + n] = f2us(acc*rn);      // A_node[n][m]
    }
  } else {
    const int n = blk-200;
    for (int h=t;h<23;h+=256) colw[h]=ws[OFF_A1E+h*100+n]*ws[OFF_RCPHN+h];
    __syncthreads();
    const float rn = ws[OFF_RCPE+n];
    u16* ae16 = (u16*)(ws + OFF_AEDGET16);
    for (int m=t;m<100;m+=256){
      float acc=0.f;
      for (int h=0;h<23;h++) acc += colw[h]*ws[OFF_A1E+h*100+m];
      ae16[m*100 + n] = f2us(acc*rn);      // A_edge[n][m] at [m][n]
    }
  }
}

// ---------------- pre3: pack sup1/sup2 into MFMA B-fragment order (incl. zero pads) ----------------
// supB[(kk*13+nt)*7+kt][lane][8]: lane holds B[k=kt*32+quad*8+j][n=nt*16+(lane&15)]
__global__ __launch_bounds__(64) void k_pre3(float* __restrict__ ws)
{
  const int blk = blockIdx.x;               // 0..181
  const int kt = blk % 7; int tmp = blk / 7;
  const int nt = tmp % 13; const int kk = tmp / 13;
  const int L = threadIdx.x, l15 = L & 15, quad = L >> 4;
  u16* supB = (u16*)(ws + OFF_SUPB);
  #pragma unroll
  for (int jj=0;jj<8;jj++){
    int m  = kt*32 + quad*8 + jj;
    int nn = nt*16 + l15;
    float v = 0.f;
    if (m < 200 && nn < 200)
      v = kk ? ws[OFF_SUP2T + m*200 + nn] : ws[OFF_SUP + nn*200 + m];
    supB[((size_t)blk*64 + L)*8 + jj] = f2us(v);
  }
}

// ---------------- stage A (MFMA): xg_k[b,n,c] -> out channels [64:128) as bf16 scratch ----------------
__global__ __launch_bounds__(256) void k_A(
    const float* __restrict__ x, const float* __restrict__ ws, u16* __restrict__ outu)
{
  const int b = blockIdx.x, t = threadIdx.x;
  const int lane = t & 63, w = t >> 6;       // w = c-tile
  const int l15 = lane & 15, quad = lane >> 4;
  __shared__ __align__(16) u16 xT[64*232];   // xT[c][m], bf16, stride 232 (2-way-free b128 reads)
  __shared__ __align__(16) u16 xgL[200*66];  // [n][c], per-kk
  const float* xb = x + (size_t)b*12800;
  for (int i=t;i<12800;i+=256){
    int m=i>>6, c=i&63;
    xT[c*232 + m] = f2us(xb[i]);
  }
  for (int i=t;i<64*32;i+=256){              // zero K-pad m=200..231
    int c=i>>5, k=i&31;
    xT[c*232 + 200 + k] = 0;
  }
  __syncthreads();
  const u16* supB = (const u16*)(ws + OFF_SUPB);
  for (int kk=0;kk<2;kk++){
    f32x4 acc[13];
    #pragma unroll
    for (int nt=0;nt<13;nt++) acc[nt] = f32x4{0.f,0.f,0.f,0.f};
    for (int kt=0;kt<7;kt++){
      short8 af = *(const short8*)&xT[(w*16 + l15)*232 + kt*32 + quad*8];
      const u16* sb = supB + ((size_t)(kk*13*7 + kt)*64 + lane)*8;
      #pragma unroll
      for (int nt=0;nt<13;nt++){
        short8 bf = *(const short8*)(sb + (size_t)nt*(7*64*8));
        acc[nt] = __builtin_amdgcn_mfma_f32_16x16x32_bf16(af, bf, acc[nt], 0,0,0);
      }
    }
    #pragma unroll
    for (int nt=0;nt<13;nt++){
      int n = nt*16 + l15;                   // D: col=lane&15 -> n, row=quad*4+r -> c
      if (n < 200){
        #pragma unroll
        for (int r=0;r<4;r++)
          xgL[n*66 + w*16 + quad*4 + r] = f2us(acc[nt][r]);
      }
    }
    __syncthreads();
    for (int i=t;i<12800;i+=256){            // coalesced copy-out to out scratch ch[64:128)
      int n=i>>6, c=i&63;
      outu[((size_t)b*200 + n)*256 + 128 + kk*64 + c] = xgL[n*66 + c];
    }
    __syncthreads();
  }
}

// ---------------- stage B (MFMA): out[:,:,0:64] = v(256) . wFold[n] + bias ----------------
__global__ __launch_bounds__(256) void k_B(
    const float* __restrict__ x, const float* __restrict__ xtime,
    const float* __restrict__ ws, const u16* __restrict__ outu, float* __restrict__ outp)
{
  const int bt = blockIdx.x, n = blockIdx.y, t = threadIdx.x;
  const int b0 = bt*64;
  const int lane = t & 63, w = t >> 6, l15 = lane & 15, quad = lane >> 4;
  __shared__ __align__(16) u16 vL[64*264];   // [b][j], bf16, j: 0:64 x | 64:192 xg | 192:247 time | pad 0
  for (int rb = w*16; rb < w*16+16; rb++){
    const size_t base = (size_t)(b0+rb)*200 + n;
    vL[rb*264 + lane] = f2us(x[base*64 + lane]);
    ((u32*)vL)[rb*132 + 32 + lane] = ((const u32*)outu)[base*128 + 64 + lane];  // xg raw bf16 pairs
    vL[rb*264 + 192 + lane] = (lane < 55) ? f2us(xtime[(size_t)(b0+rb)*55 + lane]) : (u16)0;
  }
  __syncthreads();
  f32x4 acc[4];
  #pragma unroll
  for (int ot=0;ot<4;ot++) acc[ot] = f32x4{0.f,0.f,0.f,0.f};
  const u16* wf = (const u16*)(ws + OFF_WF16) + (size_t)n*(247*64);
  for (int kt=0;kt<8;kt++){
    short8 af = *(const short8*)&vL[(w*16 + l15)*264 + kt*32 + quad*8];
    const int kbase = kt*32 + quad*8;
    #pragma unroll
    for (int ot=0;ot<4;ot++){
      const int o = ot*16 + l15;
      short8 bf;
      if (kt < 7){
        #pragma unroll
        for (int jj=0;jj<8;jj++) bf[jj] = (short)wf[(size_t)(kbase+jj)*64 + o];
      } else {
        #pragma unroll
        for (int jj=0;jj<8;jj++){
          int k = kbase+jj;
          bf[jj] = (k < 247) ? (short)wf[(size_t)k*64 + o] : (short)0;
        }
      }
      acc[ot] = __builtin_amdgcn_mfma_f32_16x16x32_bf16(af, bf, acc[ot], 0,0,0);
    }
  }
  #pragma unroll
  for (int ot=0;ot<4;ot++){
    const int o = ot*16 + l15;               // D: col -> o, row -> b-local
    const float bias = ws[OFF_BIAS + n*128 + o];
    #pragma unroll
    for (int r=0;r<4;r++){
      const int b = b0 + w*16 + quad*4 + r;
      outp[((size_t)b*200 + n)*128 + o] = acc[ot][r] + bias;
    }
  }
}

// ---------------- per-batch chain: out[:,:,64:128] ----------------
__global__ __launch_bounds__(256) void k_chain(
    const float* __restrict__ x, const float* __restrict__ xe,
    const float* __restrict__ hodge, const float* __restrict__ inc,
    const float* __restrict__ ws, float* __restrict__ outp)
{
  const int b = blockIdx.x, t = threadIdx.x;
  const int lane = t&63;
  const int wv = __builtin_amdgcn_readfirstlane(t>>6);
  __shared__ __align__(16) float pool[13652];
  __shared__ __align__(16) float xea[800];
  __shared__ u16 xeT[16*101];
  u16*   xbTu   = (u16*)pool;
  float* xa     = pool + 6432;
  u16*   hodgeTu= (u16*)pool;
  float* hl     = pool + 6432;
  float* xeh    = pool + 8132;
  float* hh     = pool + 10052;
  u16*   incTu  = (u16*)pool;
  const u16* an16 = (const u16*)(ws + OFF_ANODET16);
  const u16* ae16 = (const u16*)(ws + OFF_AEDGET16);

  {
    const float* xf = x + (size_t)b*12800;
    for (int idx=t; idx<12800; idx+=256){
      int nn=idx>>6, j=idx&63;
      xbTu[j*201+nn] = f2us(xf[idx]);
    }
  }
  __syncthreads();
  if (t < 200){
    const int nn = t;
    float as[16], aa[16];
    #pragma unroll
    for (int c=0;c<16;c++){ as[c]=0.f; aa[c]=0.f; }
    for (int j=0;j<64;j++){
      float xv = us2f(xbTu[j*201+nn]);
      const float* Wn = ws + OFF_WNODE + j*32;
      #pragma unroll
      for (int c=0;c<16;c++){ as[c] += xv*Wn[c]; aa[c] += xv*Wn[16+c]; }
    }
    const float* bs = ws + OFF_BIAS + nn*128 + 64;
    float* op = outp + ((size_t)b*200 + nn)*128 + 64;
    #pragma unroll
    for (int c=0;c<16;c++){ op[c] = as[c] + bs[c]; xa[nn*16+c] = aa[c]; }
  }
  __syncthreads();
  if (lane < 50){
    const int nn = wv*50 + lane;
    float acc[16];
    #pragma unroll
    for (int c=0;c<16;c++) acc[c]=0.f;
    for (int m=0;m<200;m++){
      float av = us2f(an16[m*200 + nn]);
      #pragma unroll
      for (int q=0;q<4;q++){
        const float4 h = *(const float4*)&xa[m*16 + q*4];
        acc[q*4+0]+=av*h.x; acc[q*4+1]+=av*h.y; acc[q*4+2]+=av*h.z; acc[q*4+3]+=av*h.w;
      }
    }
    const float* bs = ws + OFF_BIAS + nn*128 + 80;
    float* op = outp + ((size_t)b*200 + nn)*128 + 80;
    #pragma unroll
    for (int c=0;c<16;c++) op[c] = acc[c] + bs[c];
  }
  __syncthreads();
  {
    const float* xef = xe + (size_t)b*1600;
    for (int idx=t; idx<1600; idx+=256){
      int m=idx>>4, j=idx&15;
      xeT[j*101+m] = f2us(xef[idx]);
    }
    for (int idx=t; idx<10000; idx+=256){
      int m=idx/100, j=idx-m*100;
      hodgeTu[j*101+m] = f2us(hodge[idx]);
    }
  }
  __syncthreads();
  if (t < 100){
    const int m = t;
    float as[8], aa[8];
    #pragma unroll
    for (int c=0;c<8;c++){ as[c]=0.f; aa[c]=0.f; }
    for (int j=0;j<16;j++){
      float xv = us2f(xeT[j*101+m]);
      const float* We = ws + OFF_WEDGE + j*16;
      #pragma unroll
      for (int c=0;c<8;c++){ as[c]+=xv*We[c]; aa[c]+=xv*We[8+c]; }
    }
    #pragma unroll
    for (int c=0;c<8;c++){ xeh[m*16+c]=as[c]; xea[m*8+c]=aa[c]; }
  }
  __syncthreads();
  if (t < 100){
    const int m = t;
    float acc[8];
    #pragma unroll
    for (int c=0;c<8;c++) acc[c]=0.f;
    for (int j=0;j<100;j++){
      float av = us2f(ae16[j*100 + m]);
      const float4 h0 = *(const float4*)&xea[j*8];
      const float4 h1 = *(const float4*)&xea[j*8+4];
      acc[0]+=av*h0.x; acc[1]+=av*h0.y; acc[2]+=av*h0.z; acc[3]+=av*h0.w;
      acc[4]+=av*h1.x; acc[5]+=av*h1.y; acc[6]+=av*h1.z; acc[7]+=av*h1.w;
    }
    #pragma unroll
    for (int c=0;c<8;c++) xeh[m*16+8+c]=acc[c];
  }
  __syncthreads();
  if (t < 200){
    const int m  = (t<100)? t : t-100;
    const int ch = (t<100)? 0 : 8;
    float acc[8];
    #pragma unroll
    for (int c=0;c<8;c++) acc[c]=0.f;
    for (int j=0;j<100;j++){
      float hv = us2f(hodgeTu[j*101+m]);
      const float4 h0 = *(const float4*)&xeh[j*16+ch];
      const float4 h1 = *(const float4*)&xeh[j*16+ch+4];
      acc[0]+=hv*h0.x; acc[1]+=hv*h0.y; acc[2]+=hv*h0.z; acc[3]+=hv*h0.w;
      acc[4]+=hv*h1.x; acc[5]+=hv*h1.y; acc[6]+=hv*h1.z; acc[7]+=hv*h1.w;
    }
    #pragma unroll
    for (int c=0;c<8;c++) hl[m*17+ch+c]=acc[c];
  }
  __syncthreads();
  if (t < 100){
    const int m = t;
    float acc[16];
    #pragma unroll
    for (int c=0;c<16;c++) acc[c]=0.f;
    for (int j=0;j<16;j++){
      float hv = hl[m*17+j];
      const float* Wh = ws + OFF_WHOC + j*16;
      #pragma unroll
      for (int c=0;c<16;c++) acc[c]+=hv*Wh[c];
    }
    const float* bh = ws + OFF_BHOC;
    #pragma unroll
    for (int c=0;c<16;c++) hh[m*36+16+c] = acc[c]+bh[c];
  }
  __syncthreads();
  for (int idx=t; idx<1600; idx+=256){
    int m=idx>>4, c=idx&15;
    hh[m*36+c] = xeh[m*16+c];
  }
  __syncthreads();
  for (int idx=t; idx<20000; idx+=256){
    int n2=idx/100, m=idx-n2*100;
    incTu[m*201+n2] = f2us(inc[idx]);
  }
  __syncthreads();
  if (lane < 50){
    const int nn = wv*50 + lane;
    float acc[32];
    #pragma unroll
    for (int c=0;c<32;c++) acc[c]=0.f;
    for (int m=0;m<100;m++){
      float iv = us2f(incTu[m*201+nn]);
      #pragma unroll
      for (int q=0;q<8;q++){
        const float4 h = *(const float4*)&hh[m*36 + q*4];
        acc[q*4+0]+=iv*h.x; acc[q*4+1]+=iv*h.y; acc[q*4+2]+=iv*h.z; acc[q*4+3]+=iv*h.w;
      }
    }
    const float* bs = ws + OFF_BIAS + nn*128 + 96;
    float* op = outp + ((size_t)b*200 + nn)*128 + 96;
    #pragma unroll
    for (int c=0;c<32;c++) op[c] = acc[c]+bs[c];
  }
}

extern "C" void kernel_launch(void* const* d_in, const int* in_sizes, int n_in,
                              void* d_out, int out_size, void* d_ws, size_t ws_size,
                              hipStream_t stream)
{
  (void)in_sizes; (void)n_in; (void)out_size; (void)ws_size;
  const float* x     = (const float*)d_in[0];
  const float* xe    = (const float*)d_in[1];
  const float* xtime = (const float*)d_in[2];
  // d_in[3] = x_window : unused
  const float* E     = (const float*)d_in[4];
  const float* hodge = (const float*)d_in[5];
  const float* inc   = (const float*)d_in[6];
  const int* hed     = (const int*)d_in[7];
  const int* hnd     = (const int*)d_in[8];
  const float* Wp    = (const float*)d_in[9];
  const float* biasP = (const float*)d_in[10];
  const float* Wns   = (const float*)d_in[11];
  const float* Wna   = (const float*)d_in[12];
  const float* Wes   = (const float*)d_in[13];
  const float* Wea   = (const float*)d_in[14];
  const float* Whoc  = (const float*)d_in[15];
  const float* bhoc  = (const float*)d_in[16];
  float* ws   = (float*)d_ws;
  float* outp = (float*)d_out;
  u16*   outu = (u16*)d_out;

  k_pre1<<<200, 256, 0, stream>>>(E, Wp, biasP, Wns, Wna, Wes, Wea, Whoc, bhoc, hed, hnd, ws);
  k_pre2<<<300, 256, 0, stream>>>(ws);
  k_pre3<<<182, 64, 0, stream>>>(ws);
  k_A<<<512, 256, 0, stream>>>(x, ws, outu);
  k_B<<<dim3(8, 200), 256, 0, stream>>>(x, xtime, ws, outu, outp);
  k_chain<<<512, 256, 0, stream>>>(x, xe, hodge, inc, ws, outp);
}

// Round 7
// 301.570 us; speedup vs baseline: 2.0748x; 1.0658x over previous
//
#include <hip/hip_runtime.h>

typedef unsigned short u16;
typedef unsigned int   u32;
typedef __attribute__((ext_vector_type(8))) short short8;
typedef __attribute__((ext_vector_type(4))) float f32x4;

// ---- workspace layout (float offsets); total 1,920,460 fl = 7.68 MB ----
#define OFF_SUP       0        // 200x200 fp32 sup1 [n][m]
#define OFF_SUP2T     40000    // fp32 sup2[n][j] stored [j*200+n]
#define OFF_BIAS      80000    // 200x128 fp32 (pre4a adds rsInc*bhoc into ch112:128)
#define OFF_RCPHE     105600
#define OFF_RCPN      105664
#define OFF_RCPHN     105920
#define OFF_RCPE      105984
#define OFF_A1        106112   // 39x200
#define OFF_A1E       113912   // 23x100
#define OFF_WNODE     116212   // 64x32 fp32 [Wns|Wna]
#define OFF_WEDGE     118260   // 16x16 fp32 [Wes|Wea]
#define OFF_WHOC      118516   // 16x16 fp32
#define OFF_BHOC      118772   // 16 fp32
#define OFF_WECOMB    118788   // 16x48 fp32 [Wes|Wea|Wes@Whoc_top|Wea@Whoc_bot]
#define OFF_M3        119556   // 200x100 fp32 = Inc@H
#define OFF_AN16      139556   // u16[40000] A_node[n][m] at [m*200+n]
#define OFF_AE16      159556   // u16[10000] A_edge[n][m] at [m*100+n]
#define OFF_SUPB      164556   // u16[139776] sup B-frags, 3 supports
#define OFF_G12       234444   // u16[46592]  chain B-frags g12 (M1|M2)
#define OFF_G34       257740   // u16[46592]  chain B-frags g34 (M3|M4)
#define OFF_WNSB      281036   // u16[1024]   Wns B-frags (2 kt)
#define OFF_WNAB      281548   // u16[1024]   Wna B-frags (2 kt)
#define OFF_WFF       282060   // u16[3276800] wFold B-frags [n][ktp<8][ot<4][lane][8]

__device__ __forceinline__ float us2f(u16 u){
  union { float f; u32 i; } v; v.i = ((u32)u) << 16; return v.f;
}
__device__ __forceinline__ u16 f2us(float f){
  u32 u = __float_as_uint(f);
  u += 0x7FFF + ((u >> 16) & 1);           // RNE
  return (u16)(u >> 16);
}

// ---------------- pre1: softmax sup, wFold B-frags, bias, counts ----------------
__global__ __launch_bounds__(256) void k_pre1(
    const float* __restrict__ E, const float* __restrict__ Wp, const float* __restrict__ biasP,
    const float* __restrict__ Wns, const float* __restrict__ Wna,
    const float* __restrict__ Wes, const float* __restrict__ Wea,
    const float* __restrict__ Whoc, const float* __restrict__ bhoc,
    const int* __restrict__ hed, const int* __restrict__ hnd,
    float* __restrict__ ws)
{
  const int n = blockIdx.x, t = threadIdx.x;
  __shared__ float Ef[2000];
  __shared__ float arow[200];
  __shared__ float red[256];
  __shared__ int A1i[7800];
  __shared__ int A1ei[2300];
  for (int i=t;i<2000;i+=256) Ef[i] = E[i];
  __syncthreads();
  const float* En = &Ef[n*10];
  for (int m=t;m<200;m+=256){
    float s=0.f;
    #pragma unroll
    for (int d=0;d<10;d++) s += En[d]*Ef[m*10+d];
    arow[m] = fmaxf(s,0.f);
  }
  __syncthreads();
  float mv = -1e30f;
  for (int m=t;m<200;m+=256) mv = fmaxf(mv, arow[m]);
  red[t]=mv; __syncthreads();
  for (int s=128;s>0;s>>=1){ if(t<s) red[t]=fmaxf(red[t],red[t+s]); __syncthreads(); }
  mv = red[0]; __syncthreads();
  float sv=0.f;
  for (int m=t;m<200;m+=256) sv += __expf(arow[m]-mv);
  red[t]=sv; __syncthreads();
  for (int s=128;s>0;s>>=1){ if(t<s) red[t]+=red[t+s]; __syncthreads(); }
  const float inv = 1.f/red[0];
  for (int m=t;m<200;m+=256)
    ws[OFF_SUP + n*200+m] = __expf(arow[m]-mv)*inv;
  // wFold B-fragments: k zones: 0:192 x/xg1/xg2 (j=k), 192:256 xg3 (zero), 256:311 time (j=k-64)
  u16* wff = (u16*)(ws + OFF_WFF) + (size_t)n*16384;
  for (int i=t;i<16384;i+=256) wff[i]=0;
  __syncthreads();
  for (int idx=t; idx<247*64; idx+=256){
    int j = idx>>6, o = idx&63;
    float acc=0.f;
    if (j<192){
      int k=j>>6, i=j&63;
      #pragma unroll
      for (int d=0;d<10;d++) acc += En[d]*Wp[((size_t)(d*3+k)*119+i)*64+o];
    } else {
      int i = 64 + (j-192);
      #pragma unroll
      for (int k=0;k<3;k++)
        for (int d=0;d<10;d++) acc += En[d]*Wp[((size_t)(d*3+k)*119+i)*64+o];
    }
    int k = (j<192)? j : j+64;
    int ktp = k>>5; ktp = (ktp<6)? ktp : ktp-2;
    int lane2 = ((k>>3)&3)*16 + (o&15);
    wff[((ktp*4 + (o>>4))*64 + lane2)*8 + (k&7)] = f2us(acc);
  }
  for (int o=t;o<128;o+=256){
    float acc=0.f;
    #pragma unroll
    for (int d=0;d<10;d++) acc += En[d]*biasP[d*128+o];
    ws[OFF_BIAS + n*128+o]=acc;
  }
  if (n==0){
    for (int i=t;i<7800;i+=256) A1i[i]=0;
    for (int i=t;i<2300;i+=256) A1ei[i]=0;
    __syncthreads();
    for (int e=t;e<800;e+=256) atomicAdd(&A1i[hed[800+e]*200 + hed[e]], 1);
    for (int e=t;e<400;e+=256) atomicAdd(&A1ei[hnd[400+e]*100 + hnd[e]], 1);
    __syncthreads();
    for (int i=t;i<7800;i+=256) ws[OFF_A1+i]=(float)A1i[i];
    for (int i=t;i<2300;i+=256) ws[OFF_A1E+i]=(float)A1ei[i];
    for (int h=t;h<39;h+=256){ int s=0; for(int m=0;m<200;m++) s+=A1i[h*200+m]; ws[OFF_RCPHE+h]=1.f/fmaxf((float)s,1.f); }
    for (int m=t;m<200;m+=256){ int s=0; for(int h=0;h<39;h++) s+=A1i[h*200+m]; ws[OFF_RCPN+m]=1.f/fmaxf((float)s,1.f); }
    for (int h=t;h<23;h+=256){ int s=0; for(int m=0;m<100;m++) s+=A1ei[h*100+m]; ws[OFF_RCPHN+h]=1.f/fmaxf((float)s,1.f); }
    for (int m=t;m<100;m+=256){ int s=0; for(int h=0;h<23;h++) s+=A1ei[h*100+m]; ws[OFF_RCPE+m]=1.f/fmaxf((float)s,1.f); }
  }
  if (n==1){
    for (int idx=t;idx<2048;idx+=256){ int j=idx>>5,c=idx&31;
      ws[OFF_WNODE+idx]= (c<16? Wns[j*16+c] : Wna[j*16+(c-16)]); }
    { int j=t>>4, c=t&15;
      ws[OFF_WEDGE+t]= (c<8? Wes[j*8+c] : Wea[j*8+(c-8)]);
      ws[OFF_WHOC+t]= Whoc[t]; }
    if (t<16) ws[OFF_BHOC+t]= bhoc[t];
  }
}

// ---------------- pre2: sup^2 (transposed), A_node/A_edge bf16 ----------------
__global__ __launch_bounds__(256) void k_pre2(float* __restrict__ ws)
{
  const int blk = blockIdx.x, t = threadIdx.x;
  __shared__ float rowp[200];
  __shared__ float colw[64];
  if (blk < 200){
    const int n = blk;
    for (int m=t;m<200;m+=256) rowp[m]=ws[OFF_SUP+n*200+m];
    for (int h=t;h<39;h+=256) colw[h]=ws[OFF_A1+h*200+n]*ws[OFF_RCPHE+h];
    __syncthreads();
    for (int j=t;j<200;j+=256){
      float acc=0.f;
      for (int m=0;m<200;m++) acc += rowp[m]*ws[OFF_SUP+m*200+j];
      ws[OFF_SUP2T + j*200 + n] = acc;
    }
    const float rn = ws[OFF_RCPN+n];
    u16* an16 = (u16*)(ws + OFF_AN16);
    for (int m=t;m<200;m+=256){
      float acc=0.f;
      for (int h=0;h<39;h++) acc += colw[h]*ws[OFF_A1+h*200+m];
      an16[m*200 + n] = f2us(acc*rn);      // A_node[n][m]
    }
  } else {
    const int n = blk-200;
    for (int h=t;h<23;h+=256) colw[h]=ws[OFF_A1E+h*100+n]*ws[OFF_RCPHN+h];
    __syncthreads();
    const float rn = ws[OFF_RCPE+n];
    u16* ae16 = (u16*)(ws + OFF_AE16);
    for (int m=t;m<100;m+=256){
      float acc=0.f;
      for (int h=0;h<23;h++) acc += colw[h]*ws[OFF_A1E+h*100+m];
      ae16[m*100 + n] = f2us(acc*rn);      // A_edge[n][m]
    }
  }
}

// ---------------- pre3: pack sup1/sup2/A_node B-frags ----------------
__global__ __launch_bounds__(64) void k_pre3(float* __restrict__ ws)
{
  const int blk = blockIdx.x;               // 273 = 3*91
  const int kk = blk/91, rem = blk%91;
  const int nt = rem/7, kt = rem%7;
  const int L = threadIdx.x, l15 = L & 15, quad = L >> 4;
  const u16* an16 = (const u16*)(ws + OFF_AN16);
  u16* supB = (u16*)(ws + OFF_SUPB);
  #pragma unroll
  for (int jj=0;jj<8;jj++){
    int m  = kt*32 + quad*8 + jj;
    int nn = nt*16 + l15;
    float v = 0.f;
    if (m < 200 && nn < 200)
      v = (kk==0)? ws[OFF_SUP + nn*200 + m]
        : (kk==1)? ws[OFF_SUP2T + m*200 + nn]
                 : us2f(an16[m*200 + nn]);
    supB[((size_t)(kk*91 + nt*7 + kt)*64 + L)*8 + jj] = f2us(v);
  }
}

// ---------------- pre4a: M3 = Inc@H, bias += rsInc*bhoc, WeComb, Wns/Wna frags ----------------
__global__ __launch_bounds__(256) void k_pre4a(
    const float* __restrict__ inc, const float* __restrict__ hodge, float* __restrict__ ws)
{
  const int blk = blockIdx.x, t = threadIdx.x;
  if (blk < 200){
    __shared__ float incL[100];
    __shared__ float rsS;
    const int n = blk;
    if (t<100) incL[t] = inc[n*100+t];
    __syncthreads();
    if (t==0){ float s=0.f; for(int m=0;m<100;m++) s+=incL[m]; rsS=s; }
    __syncthreads();
    if (t<100){
      float a=0.f;
      for (int m=0;m<100;m++) a += incL[m]*hodge[m*100+t];
      ws[OFF_M3 + n*100 + t] = a;
    }
    if (t<16) ws[OFF_BIAS + n*128 + 112 + t] += rsS * ws[OFF_BHOC + t];
  } else if (blk == 200){
    for (int i=t;i<768;i+=256){
      int j=i/48, cc=i-(i/48)*48;
      float v;
      if (cc<16) v = ws[OFF_WEDGE + j*16 + cc];
      else if (cc<32){ v=0.f; for(int q=0;q<8;q++) v += ws[OFF_WEDGE+j*16+q]*ws[OFF_WHOC+q*16+(cc-16)]; }
      else           { v=0.f; for(int q=0;q<8;q++) v += ws[OFF_WEDGE+j*16+8+q]*ws[OFF_WHOC+(8+q)*16+(cc-32)]; }
      ws[OFF_WECOMB + i] = v;
    }
  } else {
    u16* wnsb=(u16*)(ws+OFF_WNSB); u16* wnab=(u16*)(ws+OFF_WNAB);
    for (int i=t;i<1024;i+=256){
      int kt=i>>9, lane=(i>>3)&63, jj=i&7;
      int k = kt*32 + (lane>>4)*8 + jj, c = lane&15;
      wnsb[i] = f2us(ws[OFF_WNODE + k*32 + c]);
      wnab[i] = f2us(ws[OFF_WNODE + k*32 + 16 + c]);
    }
  }
}

// ---------------- pre4b: pack chain B-frags (M1|M2) and (M3|M4) ----------------
__global__ __launch_bounds__(64) void k_pre4b(
    const float* __restrict__ inc, float* __restrict__ ws)
{
  const int blk = blockIdx.x;               // 182 = 2*91
  const int g = blk/91, rem = blk%91;
  const int nt = rem/7, kt = rem%7;
  const int L = threadIdx.x, l15 = L & 15, quad = L >> 4;
  const u16* ae16 = (const u16*)(ws + OFF_AE16);
  u16* G = (u16*)(ws + (g? OFF_G34 : OFF_G12));
  #pragma unroll
  for (int jj=0;jj<8;jj++){
    int k = kt*32 + quad*8 + jj;
    int n = nt*16 + l15;
    float v = 0.f;
    if (n < 200 && k < 200){
      if (g==0){
        if (k<100) v = inc[n*100+k];
        else { const float* ir = inc + n*100; const u16* ac = ae16 + (k-100)*100;
               for (int m=0;m<100;m++) v += ir[m]*us2f(ac[m]); }
      } else {
        if (k<100) v = ws[OFF_M3 + n*100 + k];
        else { const float* mr = ws + OFF_M3 + n*100; const u16* ac = ae16 + (k-100)*100;
               for (int m=0;m<100;m++) v += mr[m]*us2f(ac[m]); }
      }
    }
    G[((size_t)(kt*13+nt)*64 + L)*8 + jj] = f2us(v);
  }
}

// ---------------- k_A (MFMA): xg1/xg2/xg3 -> out u16 slots [64:256) ----------------
__global__ __launch_bounds__(256) void k_A(
    const float* __restrict__ x, const float* __restrict__ ws, u16* __restrict__ outu)
{
  const int b = blockIdx.x, t = threadIdx.x;
  const int lane = t & 63, w = t >> 6;
  const int l15 = lane & 15, quad = lane >> 4;
  __shared__ __align__(16) u16 xT[64*232];
  __shared__ __align__(16) u16 xgL[200*66];
  const float* xb = x + (size_t)b*12800;
  for (int i=t;i<12800;i+=256){
    int m=i>>6, c=i&63;
    xT[c*232 + m] = f2us(xb[i]);
  }
  for (int i=t;i<64*32;i+=256){
    int c=i>>5, k=i&31;
    xT[c*232 + 200 + k] = 0;
  }
  __syncthreads();
  const u16* supB = (const u16*)(ws + OFF_SUPB);
  for (int kk=0;kk<3;kk++){
    f32x4 acc[13];
    #pragma unroll
    for (int nt=0;nt<13;nt++) acc[nt] = f32x4{0.f,0.f,0.f,0.f};
    for (int kt=0;kt<7;kt++){
      short8 af = *(const short8*)&xT[(w*16 + l15)*232 + kt*32 + quad*8];
      const u16* sb = supB + ((size_t)(kk*91 + kt)*64 + lane)*8;
      #pragma unroll
      for (int nt=0;nt<13;nt++){
        short8 bf = *(const short8*)(sb + (size_t)nt*(7*64*8));
        acc[nt] = __builtin_amdgcn_mfma_f32_16x16x32_bf16(af, bf, acc[nt], 0,0,0);
      }
    }
    #pragma unroll
    for (int nt=0;nt<13;nt++){
      int n = nt*16 + l15;
      if (n < 200){
        #pragma unroll
        for (int r=0;r<4;r++)
          xgL[n*66 + w*16 + quad*4 + r] = f2us(acc[nt][r]);
      }
    }
    __syncthreads();
    for (int i=t;i<12800;i+=256){
      int n=i>>6, c=i&63;
      outu[((size_t)b*200 + n)*256 + 64 + kk*64 + c] = xgL[n*66 + c];
    }
    __syncthreads();
  }
}

// ---------------- k_B (MFMA): out ch[0:96) ----------------
__global__ __launch_bounds__(256) void k_B(
    const float* __restrict__ x, const float* __restrict__ xtime,
    const float* __restrict__ ws, const u16* __restrict__ outu, float* __restrict__ outp)
{
  const int bt = blockIdx.x, n = blockIdx.y, t = threadIdx.x;
  const int b0 = bt*64;
  const int lane = t & 63, w = t >> 6, l15 = lane & 15, quad = lane >> 4;
  __shared__ __align__(16) u16 vL[64*328];   // k: 0:64 x | 64:256 xg1/2/3 | 256:311 time | pad
  for (int i=t;i<4096;i+=256){ int rb=i>>6, j=i&63;
    vL[rb*328+j] = f2us(x[((size_t)(b0+rb)*200+n)*64+j]); }
  for (int i=t;i<6144;i+=256){ int rb=i/96, j=i-(i/96)*96;
    *(u32*)&vL[rb*328+64+2*j] = ((const u32*)outu)[((size_t)(b0+rb)*200+n)*128+32+j]; }
  for (int i=t;i<4096;i+=256){ int rb=i>>6, j=i&63;
    vL[rb*328+256+j] = (j<55)? f2us(xtime[(size_t)(b0+rb)*55+j]) : (u16)0; }
  __syncthreads();
  f32x4 acc[4], accS, accA;
  #pragma unroll
  for (int ot=0;ot<4;ot++) acc[ot] = f32x4{0.f,0.f,0.f,0.f};
  accS = f32x4{0.f,0.f,0.f,0.f};
  accA = f32x4{0.f,0.f,0.f,0.f};
  const u16* wff  = (const u16*)(ws+OFF_WFF) + (size_t)n*16384;
  const u16* wnsb = (const u16*)(ws+OFF_WNSB);
  const u16* wnab = (const u16*)(ws+OFF_WNAB);
  const int row = w*16 + l15;
  for (int ktp=0;ktp<8;ktp++){
    const int ktph = (ktp<6)? ktp : ktp+2;
    short8 af = *(const short8*)&vL[row*328 + ktph*32 + quad*8];
    #pragma unroll
    for (int ot=0;ot<4;ot++){
      short8 bf = *(const short8*)&wff[((ktp*4+ot)*64+lane)*8];
      acc[ot] = __builtin_amdgcn_mfma_f32_16x16x32_bf16(af, bf, acc[ot], 0,0,0);
    }
    if (ktp<2){
      short8 bs = *(const short8*)&wnsb[(ktp*64+lane)*8];
      accS = __builtin_amdgcn_mfma_f32_16x16x32_bf16(af, bs, accS, 0,0,0);
    }
  }
  #pragma unroll
  for (int kt2=0;kt2<2;kt2++){               // xg3 zone (phys kt 6,7) x Wna
    short8 af = *(const short8*)&vL[row*328 + (6+kt2)*32 + quad*8];
    short8 bn = *(const short8*)&wnab[(kt2*64+lane)*8];
    accA = __builtin_amdgcn_mfma_f32_16x16x32_bf16(af, bn, accA, 0,0,0);
  }
  const int rbase = b0 + w*16 + quad*4;
  #pragma unroll
  for (int ot=0;ot<4;ot++){
    int o = ot*16+l15;
    float bias = ws[OFF_BIAS+n*128+o];
    #pragma unroll
    for (int r=0;r<4;r++)
      outp[((size_t)(rbase+r)*200+n)*128+o] = acc[ot][r]+bias;
  }
  { int o = 64+l15; float bias = ws[OFF_BIAS+n*128+o];
    #pragma unroll
    for (int r=0;r<4;r++)
      outp[((size_t)(rbase+r)*200+n)*128+o] = accS[r]+bias; }
  { int o = 80+l15; float bias = ws[OFF_BIAS+n*128+o];
    #pragma unroll
    for (int r=0;r<4;r++)
      outp[((size_t)(rbase+r)*200+n)*128+o] = accA[r]+bias; }
}

// ---------------- k_E (MFMA): out ch[96:128) via composed operators ----------------
__global__ __launch_bounds__(256) void k_E(
    const float* __restrict__ xe, const float* __restrict__ ws, float* __restrict__ outp)
{
  const int b = blockIdx.x, t = threadIdx.x;
  const int lane = t & 63, w = t >> 6, l15 = lane & 15, quad = lane >> 4;
  __shared__ float xeL[1600];
  __shared__ __align__(16) u16 Afr[2][16*232];
  for (int i=t;i<1600;i+=256) xeL[i] = xe[(size_t)b*1600+i];
  for (int i=t;i<3712;i+=256){ Afr[0][i]=0; Afr[1][i]=0; }
  __syncthreads();
  for (int i=t;i<4800;i+=256){
    int m = i/48, cc = i-(i/48)*48;
    float v=0.f;
    const float* wcb = ws + OFF_WECOMB + cc;
    const float* xr = xeL + m*16;
    #pragma unroll
    for (int j=0;j<16;j++) v += xr[j]*wcb[j*48];
    u16 hv = f2us(v);
    if (cc<8)       Afr[0][cc*232 + m] = hv;
    else if (cc<16) Afr[0][cc*232 + 100 + m] = hv;
    else if (cc<32) Afr[1][(cc-16)*232 + m] = hv;
    else            Afr[1][(cc-32)*232 + 100 + m] = hv;
  }
  __syncthreads();
  const int g = w & 1, half = w >> 1;
  const int nt0 = half*7;
  const u16* G = (const u16*)(ws + (g? OFF_G34 : OFF_G12));
  const u16* A = Afr[g];
  f32x4 acc[7];
  #pragma unroll
  for (int q=0;q<7;q++) acc[q] = f32x4{0.f,0.f,0.f,0.f};
  for (int kt=0;kt<7;kt++){
    short8 af = *(const short8*)&A[l15*232 + kt*32 + quad*8];
    #pragma unroll
    for (int q=0;q<7;q++){
      short8 bf = *(const short8*)&G[((size_t)(kt*13 + nt0 + q)*64 + lane)*8];
      acc[q] = __builtin_amdgcn_mfma_f32_16x16x32_bf16(af, bf, acc[q], 0,0,0);
    }
  }
  #pragma unroll
  for (int q=0;q<7;q++){
    int n = (nt0+q)*16 + l15;
    if (n < 200){
      #pragma unroll
      for (int r=0;r<4;r++){
        int ch = 96 + g*16 + quad*4 + r;
        outp[((size_t)b*200+n)*128 + ch] = acc[q][r] + ws[OFF_BIAS + n*128 + ch];
      }
    }
  }
}

extern "C" void kernel_launch(void* const* d_in, const int* in_sizes, int n_in,
                              void* d_out, int out_size, void* d_ws, size_t ws_size,
                              hipStream_t stream)
{
  (void)in_sizes; (void)n_in; (void)out_size; (void)ws_size;
  const float* x     = (const float*)d_in[0];
  const float* xe    = (const float*)d_in[1];
  const float* xtime = (const float*)d_in[2];
  // d_in[3] = x_window : unused
  const float* E     = (const float*)d_in[4];
  const float* hodge = (const float*)d_in[5];
  const float* inc   = (const float*)d_in[6];
  const int* hed     = (const int*)d_in[7];
  const int* hnd     = (const int*)d_in[8];
  const float* Wp    = (const float*)d_in[9];
  const float* biasP = (const float*)d_in[10];
  const float* Wns   = (const float*)d_in[11];
  const float* Wna   = (const float*)d_in[12];
  const float* Wes   = (const float*)d_in[13];
  const float* Wea   = (const float*)d_in[14];
  const float* Whoc  = (const float*)d_in[15];
  const float* bhoc  = (const float*)d_in[16];
  float* ws   = (float*)d_ws;
  float* outp = (float*)d_out;
  u16*   outu = (u16*)d_out;

  k_pre1<<<200, 256, 0, stream>>>(E, Wp, biasP, Wns, Wna, Wes, Wea, Whoc, bhoc, hed, hnd, ws);
  k_pre2<<<300, 256, 0, stream>>>(ws);
  k_pre3<<<273, 64, 0, stream>>>(ws);
  k_pre4a<<<202, 256, 0, stream>>>(inc, hodge, ws);
  k_pre4b<<<182, 64, 0, stream>>>(inc, ws);
  k_A<<<512, 256, 0, stream>>>(x, ws, outu);
  k_B<<<dim3(8, 200), 256, 0, stream>>>(x, xtime, ws, outu, outp);
  k_E<<<512, 256, 0, stream>>>(xe, ws, outp);
}